// Round 3
// baseline (934.049 us; speedup 1.0000x reference)
//
#include <hip/hip_runtime.h>
#include <cstdint>
#include <cstddef>

#define NN 20000   // nodes
#define NE 320000  // edges
#define NB 4       // batch
#define NF 16      // f_in
#define NH 64      // hidden
#define NP 12      // periods
#define FP (NF*NP) // 192 features per node row

// ---------------- CSR construction ----------------
// deg/counts/cursor are zeroed by one hipMemsetAsync; deg accumulates edge
// weights only (self-loop weight 1.0 is added inside rsqrt below).

__global__ __launch_bounds__(256) void k_degcount(const int* __restrict__ ei,
                                                  const float* __restrict__ ew,
                                                  float* deg, int* counts) {
    int e = blockIdx.x * 256 + threadIdx.x;
    if (e < NE) {
        int dst = ei[NE + e];
        atomicAdd(&deg[dst], ew[e]);
        atomicAdd(&counts[dst], 1);
    }
}

// Fused: blocks 0..19 -> dinv; block 20 -> exclusive scan; block 21 -> weight folding.
// H0 == 0 in the reference scan (the carry is the accumulator; the hidden state
// is the zero closure constant), so:
//   Z  = sigmoid(a @ (Wg_z @ Wl_z[:64]) + (bg_z @ Wl_z[:64] + bl_z))
//   Ht = tanh  (a @ (Wg_h @ Wl_h[:64]) + (bg_h @ Wl_h[:64] + bl_h))
//   Hn = (1-Z)*Ht          (R path multiplies H0=0 -> dead)
__global__ __launch_bounds__(1024) void k_prep(
        const float* __restrict__ deg, float* __restrict__ dinv,
        const int* __restrict__ counts, int* __restrict__ offsets,
        const float* __restrict__ Wg_z, const float* __restrict__ bg_z,
        const float* __restrict__ Wg_h, const float* __restrict__ bg_h,
        const float* __restrict__ Wl_z, const float* __restrict__ bl_z,
        const float* __restrict__ Wl_h, const float* __restrict__ bl_h,
        const float* __restrict__ att,
        float* Wz_eff, float* Wh_eff, float* bz_eff, float* bh_eff, float* probs) {
    int blk = blockIdx.x;
    int t = threadIdx.x;
    if (blk < 20) {                       // ---- dinv ----
        int i = blk * 1024 + t;
        if (i < NN) dinv[i] = rsqrtf(1.0f + deg[i]);   // +1 = self-loop weight
        return;
    }
    if (blk == 20) {                      // ---- exclusive scan counts -> offsets ----
        __shared__ int sums[1024];
        const int PER = (NN + 1023) / 1024; // 20
        int start = t * PER;
        int end   = start + PER; if (end > NN) end = NN;
        int s = 0;
        for (int i = start; i < end && start < NN; ++i) s += counts[i];
        if (start >= NN) s = 0;
        sums[t] = s;
        __syncthreads();
        for (int off = 1; off < 1024; off <<= 1) {
            int v = (t >= off) ? sums[t - off] : 0;
            __syncthreads();
            sums[t] += v;
            __syncthreads();
        }
        int run = (t == 0) ? 0 : sums[t - 1];
        for (int i = start; i < end && start < NN; ++i) { offsets[i] = run; run += counts[i]; }
        if (t == 1023) offsets[NN] = sums[1023]; // == NE
        return;
    }
    // ---- weight folding ----  t = f*64 + j
    int f = t >> 6, j = t & 63;
    float sz = 0.f, sh = 0.f;
    for (int k = 0; k < NH; ++k) {
        sz += Wg_z[f * NH + k] * Wl_z[k * NH + j];
        sh += Wg_h[f * NH + k] * Wl_h[k * NH + j];
    }
    Wz_eff[t] = sz;
    Wh_eff[t] = sh;
    if (t < NH) {
        float bz = bl_z[t], bh = bl_h[t];
        for (int k = 0; k < NH; ++k) {
            bz += bg_z[k] * Wl_z[k * NH + t];
            bh += bg_h[k] * Wl_h[k * NH + t];
        }
        bz_eff[t] = bz;
        bh_eff[t] = bh;
    }
    if (t == 0) {
        float m = att[0];
        for (int p = 1; p < NP; ++p) m = fmaxf(m, att[p]);
        float s = 0.f, e_[NP];
        for (int p = 0; p < NP; ++p) { e_[p] = expf(att[p] - m); s += e_[p]; }
        for (int p = 0; p < NP; ++p) probs[p] = e_[p] / s;
    }
}

__global__ __launch_bounds__(256) void k_fill(const int* __restrict__ ei,
                                              const float* __restrict__ ew,
                                              const float* __restrict__ dinv,
                                              const int* __restrict__ offsets,
                                              int* cursor, int* src_list, float* norm_list) {
    int e = blockIdx.x * 256 + threadIdx.x;
    if (e < NE) {
        int s = ei[e];
        int d = ei[NE + e];
        float nm = dinv[s] * ew[e] * dinv[d];
        int pos = atomicAdd(&cursor[d], 1);
        int idx = offsets[d] + pos;
        src_list[idx]  = s;
        norm_list[idx] = nm;
    }
}

// ---------------- fused aggregate + GRU + attention + output ----------------
// 1 block per node; wave w (of 4) handles batch w; lane = hidden dim (64).
// Gather loop unrolled x4: 12 independent outstanding loads per lane to cover
// memory latency (round-2 profile: latency-bound, HBM only 13% of peak).
__global__ __launch_bounds__(256, 4) void k_main(
        const float* __restrict__ x,
        const int* __restrict__ offsets, const int* __restrict__ src_list,
        const float* __restrict__ norm_list, const float* __restrict__ dinv,
        const float* __restrict__ Wz_eff, const float* __restrict__ Wh_eff,
        const float* __restrict__ bz_eff, const float* __restrict__ bh_eff,
        const float* __restrict__ probs, const float* __restrict__ W_out,
        const float* __restrict__ b_out, float* __restrict__ out) {
    __shared__ float a_lds[NB][FP];
    int n = blockIdx.x;
    int b = threadIdx.x >> 6;
    int lane = threadIdx.x & 63;

    const float* xb = x + (size_t)b * (NN * (size_t)FP);
    float di = dinv[n];
    float sw = di * di;            // self-loop norm
    const float* xn = xb + (size_t)n * FP;
    float a0 = sw * xn[lane];
    float a1 = sw * xn[64 + lane];
    float a2 = sw * xn[128 + lane];

    int beg = offsets[n], end = offsets[n + 1];
    int e = beg;
    for (; e + 4 <= end; e += 4) {
        int   s0 = src_list[e + 0], s1 = src_list[e + 1];
        int   s2 = src_list[e + 2], s3 = src_list[e + 3];
        float w0 = norm_list[e + 0], w1 = norm_list[e + 1];
        float w2 = norm_list[e + 2], w3 = norm_list[e + 3];
        const float* p0 = xb + (size_t)s0 * FP;
        const float* p1 = xb + (size_t)s1 * FP;
        const float* p2 = xb + (size_t)s2 * FP;
        const float* p3 = xb + (size_t)s3 * FP;
        float v00 = p0[lane], v01 = p0[64 + lane], v02 = p0[128 + lane];
        float v10 = p1[lane], v11 = p1[64 + lane], v12 = p1[128 + lane];
        float v20 = p2[lane], v21 = p2[64 + lane], v22 = p2[128 + lane];
        float v30 = p3[lane], v31 = p3[64 + lane], v32 = p3[128 + lane];
        a0 += w0 * v00; a1 += w0 * v01; a2 += w0 * v02;
        a0 += w1 * v10; a1 += w1 * v11; a2 += w1 * v12;
        a0 += w2 * v20; a1 += w2 * v21; a2 += w2 * v22;
        a0 += w3 * v30; a1 += w3 * v31; a2 += w3 * v32;
    }
    for (; e < end; ++e) {
        int s = src_list[e];
        float w = norm_list[e];
        const float* p = xb + (size_t)s * FP;
        a0 += w * p[lane]; a1 += w * p[64 + lane]; a2 += w * p[128 + lane];
    }
    a_lds[b][lane]       = a0;
    a_lds[b][64 + lane]  = a1;
    a_lds[b][128 + lane] = a2;
    __syncthreads();

    float Wz[NF], Wh[NF];
#pragma unroll
    for (int f = 0; f < NF; ++f) {
        Wz[f] = Wz_eff[f * NH + lane];
        Wh[f] = Wh_eff[f * NH + lane];
    }
    float bz = bz_eff[lane], bh = bh_eff[lane];

    float hacc = 0.f;
#pragma unroll
    for (int p = 0; p < NP; ++p) {
        float z = bz, h = bh;
#pragma unroll
        for (int f = 0; f < NF; ++f) {
            float a = a_lds[b][f * NP + p];   // uniform address -> LDS broadcast
            z += a * Wz[f];
            h += a * Wh[f];
        }
        float zs = 1.f / (1.f + expf(-z));
        hacc += probs[p] * (1.f - zs) * tanhf(h);
    }

    float r = fmaxf(hacc, 0.f);
    float o[NP];
#pragma unroll
    for (int k = 0; k < NP; ++k) o[k] = r * W_out[lane * NP + k];
#pragma unroll
    for (int off = 32; off > 0; off >>= 1) {
#pragma unroll
        for (int k = 0; k < NP; ++k) o[k] += __shfl_xor(o[k], off, 64);
    }
    if (lane == 0) {
        size_t ob = ((size_t)b * NN + n) * NP;
#pragma unroll
        for (int k = 0; k < NP; ++k) out[ob + k] = o[k] + b_out[k];
    }
}

// ---------------- launch ----------------

extern "C" void kernel_launch(void* const* d_in, const int* in_sizes, int n_in,
                              void* d_out, int out_size, void* d_ws, size_t ws_size,
                              hipStream_t stream) {
    const float* x     = (const float*)d_in[0];
    const int*   ei    = (const int*)d_in[1];    // int32 per harness (shape [2][NE])
    const float* ew    = (const float*)d_in[2];
    const float* Wg_z  = (const float*)d_in[3];
    const float* bg_z  = (const float*)d_in[4];
    // d_in[5], d_in[6]: Wg_r/bg_r — dead (H0==0)
    const float* Wg_h  = (const float*)d_in[7];
    const float* bg_h  = (const float*)d_in[8];
    const float* Wl_z  = (const float*)d_in[9];
    const float* bl_z  = (const float*)d_in[10];
    // d_in[11], d_in[12]: Wl_r/bl_r — dead
    const float* Wl_h  = (const float*)d_in[13];
    const float* bl_h  = (const float*)d_in[14];
    const float* att   = (const float*)d_in[15];
    const float* W_out = (const float*)d_in[16];
    const float* b_out = (const float*)d_in[17];
    float*       out   = (float*)d_out;

    char* p = (char*)d_ws;
    auto alloc = [&](size_t bytes) -> void* {
        void* r = (void*)p;
        p += (bytes + 255) & ~(size_t)255;
        return r;
    };
    // deg/counts/cursor contiguous -> one memset zeroes all three
    const size_t PAD_NN = ((size_t)NN * 4 + 255) & ~(size_t)255;
    float* deg       = (float*)alloc(NN * 4);
    int*   counts    = (int*)  alloc(NN * 4);
    int*   cursor    = (int*)  alloc(NN * 4);
    float* dinv      = (float*)alloc(NN * 4);
    int*   offsets   = (int*)  alloc((NN + 1) * 4);
    int*   src_list  = (int*)  alloc(NE * 4);
    float* norm_list = (float*)alloc(NE * 4);
    float* Wz_eff    = (float*)alloc(NF * NH * 4);
    float* Wh_eff    = (float*)alloc(NF * NH * 4);
    float* bz_eff    = (float*)alloc(NH * 4);
    float* bh_eff    = (float*)alloc(NH * 4);
    float* probs     = (float*)alloc(16 * 4);

    hipMemsetAsync(deg, 0, PAD_NN * 3, stream);

    k_degcount<<<(NE + 255) / 256, 256, 0, stream>>>(ei, ew, deg, counts);
    k_prep    <<<22, 1024, 0, stream>>>(deg, dinv, counts, offsets,
                                        Wg_z, bg_z, Wg_h, bg_h, Wl_z, bl_z, Wl_h, bl_h, att,
                                        Wz_eff, Wh_eff, bz_eff, bh_eff, probs);
    k_fill    <<<(NE + 255) / 256, 256, 0, stream>>>(ei, ew, dinv, offsets, cursor, src_list, norm_list);
    k_main    <<<NN, 256, 0, stream>>>(x, offsets, src_list, norm_list, dinv,
                                       Wz_eff, Wh_eff, bz_eff, bh_eff, probs, W_out, b_out, out);
}

// Round 4
// 411.014 us; speedup vs baseline: 2.2725x; 2.2725x over previous
//
#include <hip/hip_runtime.h>
#include <cstdint>
#include <cstddef>

#define NN 20000   // nodes
#define NE 320000  // edges
#define NB 4       // batch
#define NF 16      // f_in
#define NH 64      // hidden
#define NP 12      // periods
#define FP (NF*NP) // 192 features per node row

// ---------------- CSR construction ----------------
// deg/counts/cursor are zeroed by one hipMemsetAsync; deg accumulates edge
// weights only (self-loop weight 1.0 is added inside rsqrt below).

__global__ __launch_bounds__(256) void k_degcount(const int* __restrict__ ei,
                                                  const float* __restrict__ ew,
                                                  float* deg, int* counts) {
    int e = blockIdx.x * 256 + threadIdx.x;
    if (e < NE) {
        int dst = ei[NE + e];
        atomicAdd(&deg[dst], ew[e]);
        atomicAdd(&counts[dst], 1);
    }
}

// Fused: blocks 0..19 -> dinv; block 20 -> exclusive scan; block 21 -> weight folding.
// H0 == 0 in the reference scan (the carry is the accumulator; the hidden state
// is the zero closure constant), so:
//   Z  = sigmoid(a @ (Wg_z @ Wl_z[:64]) + (bg_z @ Wl_z[:64] + bl_z))
//   Ht = tanh  (a @ (Wg_h @ Wl_h[:64]) + (bg_h @ Wl_h[:64] + bl_h))
//   Hn = (1-Z)*Ht          (R path multiplies H0=0 -> dead)
__global__ __launch_bounds__(1024) void k_prep(
        const float* __restrict__ deg, float* __restrict__ dinv,
        const int* __restrict__ counts, int* __restrict__ offsets,
        const float* __restrict__ Wg_z, const float* __restrict__ bg_z,
        const float* __restrict__ Wg_h, const float* __restrict__ bg_h,
        const float* __restrict__ Wl_z, const float* __restrict__ bl_z,
        const float* __restrict__ Wl_h, const float* __restrict__ bl_h,
        const float* __restrict__ att,
        float* Wz_eff, float* Wh_eff, float* bz_eff, float* bh_eff, float* probs) {
    int blk = blockIdx.x;
    int t = threadIdx.x;
    if (blk < 20) {                       // ---- dinv ----
        int i = blk * 1024 + t;
        if (i < NN) dinv[i] = rsqrtf(1.0f + deg[i]);   // +1 = self-loop weight
        return;
    }
    if (blk == 20) {                      // ---- exclusive scan counts -> offsets ----
        __shared__ int sums[1024];
        const int PER = (NN + 1023) / 1024; // 20
        int start = t * PER;
        int end   = start + PER; if (end > NN) end = NN;
        int s = 0;
        for (int i = start; i < end && start < NN; ++i) s += counts[i];
        if (start >= NN) s = 0;
        sums[t] = s;
        __syncthreads();
        for (int off = 1; off < 1024; off <<= 1) {
            int v = (t >= off) ? sums[t - off] : 0;
            __syncthreads();
            sums[t] += v;
            __syncthreads();
        }
        int run = (t == 0) ? 0 : sums[t - 1];
        for (int i = start; i < end && start < NN; ++i) { offsets[i] = run; run += counts[i]; }
        if (t == 1023) offsets[NN] = sums[1023]; // == NE
        return;
    }
    // ---- weight folding ----  t = f*64 + j
    int f = t >> 6, j = t & 63;
    float sz = 0.f, sh = 0.f;
    for (int k = 0; k < NH; ++k) {
        sz += Wg_z[f * NH + k] * Wl_z[k * NH + j];
        sh += Wg_h[f * NH + k] * Wl_h[k * NH + j];
    }
    Wz_eff[t] = sz;
    Wh_eff[t] = sh;
    if (t < NH) {
        float bz = bl_z[t], bh = bl_h[t];
        for (int k = 0; k < NH; ++k) {
            bz += bg_z[k] * Wl_z[k * NH + t];
            bh += bg_h[k] * Wl_h[k * NH + t];
        }
        bz_eff[t] = bz;
        bh_eff[t] = bh;
    }
    if (t == 0) {
        float m = att[0];
        for (int p = 1; p < NP; ++p) m = fmaxf(m, att[p]);
        float s = 0.f, e_[NP];
        for (int p = 0; p < NP; ++p) { e_[p] = expf(att[p] - m); s += e_[p]; }
        for (int p = 0; p < NP; ++p) probs[p] = e_[p] / s;
    }
}

__global__ __launch_bounds__(256) void k_fill(const int* __restrict__ ei,
                                              const float* __restrict__ ew,
                                              const float* __restrict__ dinv,
                                              const int* __restrict__ offsets,
                                              int* cursor, int* src_list, float* norm_list) {
    int e = blockIdx.x * 256 + threadIdx.x;
    if (e < NE) {
        int s = ei[e];
        int d = ei[NE + e];
        float nm = dinv[s] * ew[e] * dinv[d];
        int pos = atomicAdd(&cursor[d], 1);
        int idx = offsets[d] + pos;
        src_list[idx]  = s;
        norm_list[idx] = nm;
    }
}

// ---------------- fused aggregate + GRU + attention + output ----------------
// 1 block per node; wave w (of 4) handles batch w; lane = hidden dim (64).
// Gather loop unrolled x4 -> 12 independent outstanding loads per lane.
// NO min-waves clamp: round-3's __launch_bounds__(256,4) capped VGPRs at 64
// and the unroll spilled (WRITE_SIZE 5MB -> 2.3GB, dur 2x worse). ILP needs
// the registers; let the allocator have them.
__global__ __launch_bounds__(256) void k_main(
        const float* __restrict__ x,
        const int* __restrict__ offsets, const int* __restrict__ src_list,
        const float* __restrict__ norm_list, const float* __restrict__ dinv,
        const float* __restrict__ Wz_eff, const float* __restrict__ Wh_eff,
        const float* __restrict__ bz_eff, const float* __restrict__ bh_eff,
        const float* __restrict__ probs, const float* __restrict__ W_out,
        const float* __restrict__ b_out, float* __restrict__ out) {
    __shared__ float a_lds[NB][FP];
    int n = blockIdx.x;
    int b = threadIdx.x >> 6;
    int lane = threadIdx.x & 63;

    const float* xb = x + (size_t)b * (NN * (size_t)FP);
    float di = dinv[n];
    float sw = di * di;            // self-loop norm
    const float* xn = xb + (size_t)n * FP;
    float a0 = sw * xn[lane];
    float a1 = sw * xn[64 + lane];
    float a2 = sw * xn[128 + lane];

    int beg = offsets[n], end = offsets[n + 1];
    int e = beg;
    for (; e + 4 <= end; e += 4) {
        int   s0 = src_list[e + 0], s1 = src_list[e + 1];
        int   s2 = src_list[e + 2], s3 = src_list[e + 3];
        float w0 = norm_list[e + 0], w1 = norm_list[e + 1];
        float w2 = norm_list[e + 2], w3 = norm_list[e + 3];
        const float* p0 = xb + (size_t)s0 * FP;
        const float* p1 = xb + (size_t)s1 * FP;
        const float* p2 = xb + (size_t)s2 * FP;
        const float* p3 = xb + (size_t)s3 * FP;
        float v00 = p0[lane], v01 = p0[64 + lane], v02 = p0[128 + lane];
        float v10 = p1[lane], v11 = p1[64 + lane], v12 = p1[128 + lane];
        float v20 = p2[lane], v21 = p2[64 + lane], v22 = p2[128 + lane];
        float v30 = p3[lane], v31 = p3[64 + lane], v32 = p3[128 + lane];
        a0 += w0 * v00; a1 += w0 * v01; a2 += w0 * v02;
        a0 += w1 * v10; a1 += w1 * v11; a2 += w1 * v12;
        a0 += w2 * v20; a1 += w2 * v21; a2 += w2 * v22;
        a0 += w3 * v30; a1 += w3 * v31; a2 += w3 * v32;
    }
    for (; e < end; ++e) {
        int s = src_list[e];
        float w = norm_list[e];
        const float* p = xb + (size_t)s * FP;
        a0 += w * p[lane]; a1 += w * p[64 + lane]; a2 += w * p[128 + lane];
    }
    a_lds[b][lane]       = a0;
    a_lds[b][64 + lane]  = a1;
    a_lds[b][128 + lane] = a2;
    __syncthreads();

    float Wz[NF], Wh[NF];
#pragma unroll
    for (int f = 0; f < NF; ++f) {
        Wz[f] = Wz_eff[f * NH + lane];
        Wh[f] = Wh_eff[f * NH + lane];
    }
    float bz = bz_eff[lane], bh = bh_eff[lane];

    float hacc = 0.f;
#pragma unroll
    for (int p = 0; p < NP; ++p) {
        float z = bz, h = bh;
#pragma unroll
        for (int f = 0; f < NF; ++f) {
            float a = a_lds[b][f * NP + p];   // uniform address -> LDS broadcast
            z += a * Wz[f];
            h += a * Wh[f];
        }
        float zs = 1.f / (1.f + expf(-z));
        hacc += probs[p] * (1.f - zs) * tanhf(h);
    }

    float r = fmaxf(hacc, 0.f);
    float o[NP];
#pragma unroll
    for (int k = 0; k < NP; ++k) o[k] = r * W_out[lane * NP + k];
#pragma unroll
    for (int off = 32; off > 0; off >>= 1) {
#pragma unroll
        for (int k = 0; k < NP; ++k) o[k] += __shfl_xor(o[k], off, 64);
    }
    if (lane == 0) {
        size_t ob = ((size_t)b * NN + n) * NP;
#pragma unroll
        for (int k = 0; k < NP; ++k) out[ob + k] = o[k] + b_out[k];
    }
}

// ---------------- launch ----------------

extern "C" void kernel_launch(void* const* d_in, const int* in_sizes, int n_in,
                              void* d_out, int out_size, void* d_ws, size_t ws_size,
                              hipStream_t stream) {
    const float* x     = (const float*)d_in[0];
    const int*   ei    = (const int*)d_in[1];    // int32 per harness (shape [2][NE])
    const float* ew    = (const float*)d_in[2];
    const float* Wg_z  = (const float*)d_in[3];
    const float* bg_z  = (const float*)d_in[4];
    // d_in[5], d_in[6]: Wg_r/bg_r — dead (H0==0)
    const float* Wg_h  = (const float*)d_in[7];
    const float* bg_h  = (const float*)d_in[8];
    const float* Wl_z  = (const float*)d_in[9];
    const float* bl_z  = (const float*)d_in[10];
    // d_in[11], d_in[12]: Wl_r/bl_r — dead
    const float* Wl_h  = (const float*)d_in[13];
    const float* bl_h  = (const float*)d_in[14];
    const float* att   = (const float*)d_in[15];
    const float* W_out = (const float*)d_in[16];
    const float* b_out = (const float*)d_in[17];
    float*       out   = (float*)d_out;

    char* p = (char*)d_ws;
    auto alloc = [&](size_t bytes) -> void* {
        void* r = (void*)p;
        p += (bytes + 255) & ~(size_t)255;
        return r;
    };
    // deg/counts/cursor contiguous -> one memset zeroes all three
    const size_t PAD_NN = ((size_t)NN * 4 + 255) & ~(size_t)255;
    float* deg       = (float*)alloc(NN * 4);
    int*   counts    = (int*)  alloc(NN * 4);
    int*   cursor    = (int*)  alloc(NN * 4);
    float* dinv      = (float*)alloc(NN * 4);
    int*   offsets   = (int*)  alloc((NN + 1) * 4);
    int*   src_list  = (int*)  alloc(NE * 4);
    float* norm_list = (float*)alloc(NE * 4);
    float* Wz_eff    = (float*)alloc(NF * NH * 4);
    float* Wh_eff    = (float*)alloc(NF * NH * 4);
    float* bz_eff    = (float*)alloc(NH * 4);
    float* bh_eff    = (float*)alloc(NH * 4);
    float* probs     = (float*)alloc(16 * 4);

    hipMemsetAsync(deg, 0, PAD_NN * 3, stream);

    k_degcount<<<(NE + 255) / 256, 256, 0, stream>>>(ei, ew, deg, counts);
    k_prep    <<<22, 1024, 0, stream>>>(deg, dinv, counts, offsets,
                                        Wg_z, bg_z, Wg_h, bg_h, Wl_z, bl_z, Wl_h, bl_h, att,
                                        Wz_eff, Wh_eff, bz_eff, bh_eff, probs);
    k_fill    <<<(NE + 255) / 256, 256, 0, stream>>>(ei, ew, dinv, offsets, cursor, src_list, norm_list);
    k_main    <<<NN, 256, 0, stream>>>(x, offsets, src_list, norm_list, dinv,
                                       Wz_eff, Wh_eff, bz_eff, bh_eff, probs, W_out, b_out, out);
}

// Round 5
// 274.750 us; speedup vs baseline: 3.3996x; 1.4960x over previous
//
#include <hip/hip_runtime.h>
#include <cstdint>
#include <cstddef>

#define NN 20000   // nodes
#define NE 320000  // edges
#define NB 4       // batch
#define NF 16      // f_in
#define NH 64      // hidden
#define NP 12      // periods
#define FP (NF*NP) // 192 features per node row

typedef _Float16 h4_t __attribute__((ext_vector_type(4)));

// ---------------- convert x to fp16 + degree/count ----------------
// blocks [0, 15000): convert x (float4 -> 4 halves); blocks [15000, 16250): degcount.
// 15000*256*4 = 15,360,000 floats = B*N*F*P exactly; 1250*256 = 320,000 edges exactly.
__global__ __launch_bounds__(256) void k_pre1(const float* __restrict__ x,
                                              _Float16* __restrict__ xh,
                                              const int* __restrict__ ei,
                                              const float* __restrict__ ew,
                                              float* deg, int* counts) {
    int blk = blockIdx.x;
    if (blk < 15000) {
        int i = blk * 256 + threadIdx.x;
        float4 v = ((const float4*)x)[i];
        h4_t o = { (_Float16)v.x, (_Float16)v.y, (_Float16)v.z, (_Float16)v.w };
        ((h4_t*)xh)[i] = o;
    } else {
        int e = (blk - 15000) * 256 + threadIdx.x;
        int dst = ei[NE + e];
        atomicAdd(&deg[dst], ew[e]);
        atomicAdd(&counts[dst], 1);
    }
}

// Fused: blocks 0..19 -> dinv; block 20 -> exclusive scan; block 21 -> weight folding.
// H0 == 0 in the reference scan (the carry is the accumulator; the hidden state
// is the zero closure constant), so:
//   Z  = sigmoid(a @ (Wg_z @ Wl_z[:64]) + (bg_z @ Wl_z[:64] + bl_z))
//   Ht = tanh  (a @ (Wg_h @ Wl_h[:64]) + (bg_h @ Wl_h[:64] + bl_h))
//   Hn = (1-Z)*Ht          (R path multiplies H0=0 -> dead)
__global__ __launch_bounds__(1024) void k_prep(
        const float* __restrict__ deg, float* __restrict__ dinv,
        const int* __restrict__ counts, int* __restrict__ offsets,
        const float* __restrict__ Wg_z, const float* __restrict__ bg_z,
        const float* __restrict__ Wg_h, const float* __restrict__ bg_h,
        const float* __restrict__ Wl_z, const float* __restrict__ bl_z,
        const float* __restrict__ Wl_h, const float* __restrict__ bl_h,
        const float* __restrict__ att,
        float* Wz_eff, float* Wh_eff, float* bz_eff, float* bh_eff, float* probs) {
    int blk = blockIdx.x;
    int t = threadIdx.x;
    if (blk < 20) {                       // ---- dinv ----
        int i = blk * 1024 + t;
        if (i < NN) dinv[i] = rsqrtf(1.0f + deg[i]);   // +1 = self-loop weight
        return;
    }
    if (blk == 20) {                      // ---- exclusive scan counts -> offsets ----
        __shared__ int sums[1024];
        const int PER = (NN + 1023) / 1024; // 20
        int start = t * PER;
        int end   = start + PER; if (end > NN) end = NN;
        int s = 0;
        for (int i = start; i < end && start < NN; ++i) s += counts[i];
        if (start >= NN) s = 0;
        sums[t] = s;
        __syncthreads();
        for (int off = 1; off < 1024; off <<= 1) {
            int v = (t >= off) ? sums[t - off] : 0;
            __syncthreads();
            sums[t] += v;
            __syncthreads();
        }
        int run = (t == 0) ? 0 : sums[t - 1];
        for (int i = start; i < end && start < NN; ++i) { offsets[i] = run; run += counts[i]; }
        if (t == 1023) offsets[NN] = sums[1023]; // == NE
        return;
    }
    // ---- weight folding ----  t = f*64 + j
    int f = t >> 6, j = t & 63;
    float sz = 0.f, sh = 0.f;
    for (int k = 0; k < NH; ++k) {
        sz += Wg_z[f * NH + k] * Wl_z[k * NH + j];
        sh += Wg_h[f * NH + k] * Wl_h[k * NH + j];
    }
    Wz_eff[t] = sz;
    Wh_eff[t] = sh;
    if (t < NH) {
        float bz = bl_z[t], bh = bl_h[t];
        for (int k = 0; k < NH; ++k) {
            bz += bg_z[k] * Wl_z[k * NH + t];
            bh += bg_h[k] * Wl_h[k * NH + t];
        }
        bz_eff[t] = bz;
        bh_eff[t] = bh;
    }
    if (t == 0) {
        float m = att[0];
        for (int p = 1; p < NP; ++p) m = fmaxf(m, att[p]);
        float s = 0.f, e_[NP];
        for (int p = 0; p < NP; ++p) { e_[p] = expf(att[p] - m); s += e_[p]; }
        for (int p = 0; p < NP; ++p) probs[p] = e_[p] / s;
    }
}

__global__ __launch_bounds__(256) void k_fill(const int* __restrict__ ei,
                                              const float* __restrict__ ew,
                                              const float* __restrict__ dinv,
                                              const int* __restrict__ offsets,
                                              int* cursor, int* src_list, float* norm_list) {
    int e = blockIdx.x * 256 + threadIdx.x;
    if (e < NE) {
        int s = ei[e];
        int d = ei[NE + e];
        float nm = dinv[s] * ew[e] * dinv[d];
        int pos = atomicAdd(&cursor[d], 1);
        int idx = offsets[d] + pos;
        src_list[idx]  = s;
        norm_list[idx] = nm;
    }
}

// ---------------- fused aggregate + GRU + attention + output ----------------
// 1 block per node; wave w (of 4) handles batch w — waves fully independent,
// NO shared memory, NO barriers.
// Gather: fp16 rows (384 B). Half-wave h handles edge e+h; lane L in [0,32)
// loads 12 B (6 halves) -> per 2 edges ONE dwordx3 (was 6 dwords in fp32).
// Accumulator a0..a5: lane (h*32+L) holds feature elems [6L, 6L+6) partial-
// summed over its half's edges; shfl_xor(32) completes the sum.
// GRU: element f*12+p sits at lane 2f+(p>=6), reg (p%6) -> v_readlane into
// SGPR broadcast (kills the 192 LDS-broadcast reads of rounds 2-4).
__device__ __forceinline__ float rlane(float v, int srclane) {
    return __uint_as_float(__builtin_amdgcn_readlane(__float_as_uint(v), srclane));
}

__global__ __launch_bounds__(256) void k_main(
        const _Float16* __restrict__ xh,
        const int* __restrict__ offsets, const int* __restrict__ src_list,
        const float* __restrict__ norm_list, const float* __restrict__ dinv,
        const float* __restrict__ Wz_eff, const float* __restrict__ Wh_eff,
        const float* __restrict__ bz_eff, const float* __restrict__ bh_eff,
        const float* __restrict__ probs, const float* __restrict__ W_out,
        const float* __restrict__ b_out, float* __restrict__ out) {
    int n = blockIdx.x;
    int b = threadIdx.x >> 6;
    int lane = threadIdx.x & 63;
    int half = lane >> 5;
    int L = lane & 31;

    const _Float16* xb = xh + (size_t)b * ((size_t)NN * FP);

    float a0=0.f,a1=0.f,a2=0.f,a3=0.f,a4=0.f,a5=0.f;

    auto acc = [&](float w, uint3 u) {
        union HU { unsigned u; _Float16 h[2]; };
        HU ux{u.x}, uy{u.y}, uz{u.z};
        a0 = fmaf(w, (float)ux.h[0], a0);
        a1 = fmaf(w, (float)ux.h[1], a1);
        a2 = fmaf(w, (float)uy.h[0], a2);
        a3 = fmaf(w, (float)uy.h[1], a3);
        a4 = fmaf(w, (float)uz.h[0], a4);
        a5 = fmaf(w, (float)uz.h[1], a5);
    };

    // self loop (half 0 carries the weight; half 1's load is discarded via w=0)
    {
        float di = dinv[n];
        float w = half ? 0.f : di * di;
        uint3 u = *(const uint3*)(xb + (size_t)n * FP + L * 6);
        acc(w, u);
    }

    int beg = offsets[n], end = offsets[n + 1];
    int e = beg;
    for (; e + 4 <= end; e += 4) {                 // 4 edges, 2 dwordx3 in flight
        int i0 = e + half, i1 = e + 2 + half;
        int   sA = src_list[i0]; float wA = norm_list[i0];
        int   sB = src_list[i1]; float wB = norm_list[i1];
        uint3 uA = *(const uint3*)(xb + (size_t)sA * FP + L * 6);
        uint3 uB = *(const uint3*)(xb + (size_t)sB * FP + L * 6);
        acc(wA, uA);
        acc(wB, uB);
    }
    for (; e < end; e += 2) {                      // remainder (1 or 2 edges)
        int i0 = e + half;
        bool v = i0 < end;
        int ic = v ? i0 : e;                       // e < end here -> safe index
        int   s = src_list[ic];
        float w = v ? norm_list[ic] : 0.f;
        uint3 u = *(const uint3*)(xb + (size_t)s * FP + L * 6);
        acc(w, u);
    }

    // complete the cross-half sums: every lane now has the full a-elements
    a0 += __shfl_xor(a0, 32, 64);
    a1 += __shfl_xor(a1, 32, 64);
    a2 += __shfl_xor(a2, 32, 64);
    a3 += __shfl_xor(a3, 32, 64);
    a4 += __shfl_xor(a4, 32, 64);
    a5 += __shfl_xor(a5, 32, 64);

    // per-lane (j = lane) effective weights
    float Wz[NF], Wh[NF];
#pragma unroll
    for (int f = 0; f < NF; ++f) {
        Wz[f] = Wz_eff[f * NH + lane];
        Wh[f] = Wh_eff[f * NH + lane];
    }
    float bz = bz_eff[lane], bh = bh_eff[lane];

    float z[NP], h[NP];
#pragma unroll
    for (int p = 0; p < NP; ++p) { z[p] = bz; h[p] = bh; }

#pragma unroll
    for (int f = 0; f < NF; ++f) {
        int l0 = 2 * f, l1 = 2 * f + 1;
        float af[NP];
        af[0]  = rlane(a0, l0); af[1]  = rlane(a1, l0); af[2]  = rlane(a2, l0);
        af[3]  = rlane(a3, l0); af[4]  = rlane(a4, l0); af[5]  = rlane(a5, l0);
        af[6]  = rlane(a0, l1); af[7]  = rlane(a1, l1); af[8]  = rlane(a2, l1);
        af[9]  = rlane(a3, l1); af[10] = rlane(a4, l1); af[11] = rlane(a5, l1);
#pragma unroll
        for (int p = 0; p < NP; ++p) {
            z[p] = fmaf(af[p], Wz[f], z[p]);
            h[p] = fmaf(af[p], Wh[f], h[p]);
        }
    }

    float hacc = 0.f;
#pragma unroll
    for (int p = 0; p < NP; ++p) {
        float zs = 1.f / (1.f + __expf(-z[p]));            // sigmoid
        float ex = __expf(2.f * h[p]);
        float th = 1.f - 2.f / (ex + 1.f);                 // tanh
        hacc = fmaf(probs[p], (1.f - zs) * th, hacc);
    }

    float r = fmaxf(hacc, 0.f);
    float o[NP];
#pragma unroll
    for (int k = 0; k < NP; ++k) o[k] = r * W_out[lane * NP + k];
#pragma unroll
    for (int off = 32; off > 0; off >>= 1) {
#pragma unroll
        for (int k = 0; k < NP; ++k) o[k] += __shfl_xor(o[k], off, 64);
    }
    if (lane == 0) {
        size_t ob = ((size_t)b * NN + n) * NP;
#pragma unroll
        for (int k = 0; k < NP; ++k) out[ob + k] = o[k] + b_out[k];
    }
}

// ---------------- launch ----------------

extern "C" void kernel_launch(void* const* d_in, const int* in_sizes, int n_in,
                              void* d_out, int out_size, void* d_ws, size_t ws_size,
                              hipStream_t stream) {
    const float* x     = (const float*)d_in[0];
    const int*   ei    = (const int*)d_in[1];    // int32 per harness (shape [2][NE])
    const float* ew    = (const float*)d_in[2];
    const float* Wg_z  = (const float*)d_in[3];
    const float* bg_z  = (const float*)d_in[4];
    // d_in[5], d_in[6]: Wg_r/bg_r — dead (H0==0)
    const float* Wg_h  = (const float*)d_in[7];
    const float* bg_h  = (const float*)d_in[8];
    const float* Wl_z  = (const float*)d_in[9];
    const float* bl_z  = (const float*)d_in[10];
    // d_in[11], d_in[12]: Wl_r/bl_r — dead
    const float* Wl_h  = (const float*)d_in[13];
    const float* bl_h  = (const float*)d_in[14];
    const float* att   = (const float*)d_in[15];
    const float* W_out = (const float*)d_in[16];
    const float* b_out = (const float*)d_in[17];
    float*       out   = (float*)d_out;

    char* p = (char*)d_ws;
    auto alloc = [&](size_t bytes) -> void* {
        void* r = (void*)p;
        p += (bytes + 255) & ~(size_t)255;
        return r;
    };
    // deg/counts/cursor contiguous -> one memset zeroes all three
    const size_t PAD_NN = ((size_t)NN * 4 + 255) & ~(size_t)255;
    float*     deg       = (float*)alloc(NN * 4);
    int*       counts    = (int*)  alloc(NN * 4);
    int*       cursor    = (int*)  alloc(NN * 4);
    float*     dinv      = (float*)alloc(NN * 4);
    int*       offsets   = (int*)  alloc((NN + 1) * 4);
    int*       src_list  = (int*)  alloc(NE * 4);
    float*     norm_list = (float*)alloc(NE * 4);
    float*     Wz_eff    = (float*)alloc(NF * NH * 4);
    float*     Wh_eff    = (float*)alloc(NF * NH * 4);
    float*     bz_eff    = (float*)alloc(NH * 4);
    float*     bh_eff    = (float*)alloc(NH * 4);
    float*     probs     = (float*)alloc(16 * 4);
    _Float16*  xh        = (_Float16*)alloc((size_t)NB * NN * FP * 2);  // 30.72 MB

    hipMemsetAsync(deg, 0, PAD_NN * 3, stream);

    k_pre1 <<<16250, 256, 0, stream>>>(x, xh, ei, ew, deg, counts);
    k_prep <<<22, 1024, 0, stream>>>(deg, dinv, counts, offsets,
                                     Wg_z, bg_z, Wg_h, bg_h, Wl_z, bl_z, Wl_h, bl_h, att,
                                     Wz_eff, Wh_eff, bz_eff, bh_eff, probs);
    k_fill <<<(NE + 255) / 256, 256, 0, stream>>>(ei, ew, dinv, offsets, cursor, src_list, norm_list);
    k_main <<<NN, 256, 0, stream>>>(xh, offsets, src_list, norm_list, dinv,
                                    Wz_eff, Wh_eff, bz_eff, bh_eff, probs, W_out, b_out, out);
}

// Round 6
// 242.354 us; speedup vs baseline: 3.8541x; 1.1337x over previous
//
#include <hip/hip_runtime.h>
#include <cstdint>
#include <cstddef>

#define NN 20000   // nodes
#define NE 320000  // edges
#define NB 4       // batch
#define NF 16      // f_in
#define NH 64      // hidden
#define NP 12      // periods
#define FP (NF*NP) // 192 features per node row

typedef _Float16 h4_t __attribute__((ext_vector_type(4)));
typedef float    f4_t __attribute__((ext_vector_type(4)));
typedef _Float16 hh4  __attribute__((ext_vector_type(4)));

// ---------------- convert x to fp16 + degree/count ----------------
// blocks [0, 15000): convert x (float4 -> 4 halves); blocks [15000, 16250): degcount.
__global__ __launch_bounds__(256) void k_pre1(const float* __restrict__ x,
                                              _Float16* __restrict__ xh,
                                              const int* __restrict__ ei,
                                              const float* __restrict__ ew,
                                              float* deg, int* counts) {
    int blk = blockIdx.x;
    if (blk < 15000) {
        int i = blk * 256 + threadIdx.x;
        float4 v = ((const float4*)x)[i];
        h4_t o = { (_Float16)v.x, (_Float16)v.y, (_Float16)v.z, (_Float16)v.w };
        ((h4_t*)xh)[i] = o;
    } else {
        int e = (blk - 15000) * 256 + threadIdx.x;
        int dst = ei[NE + e];
        atomicAdd(&deg[dst], ew[e]);
        atomicAdd(&counts[dst], 1);
    }
}

// Fused: blocks 0..19 -> dinv; block 20 -> scan; block 21 -> weight folding +
// f16 MFMA B-fragment packing + biases + probs.
// H0 == 0 in the reference (carry is the accumulator), so:
//   Z  = sigmoid(a @ (Wg_z @ Wl_z[:64]) + (bg_z @ Wl_z[:64] + bl_z))
//   Ht = tanh  (a @ (Wg_h @ Wl_h[:64]) + (bg_h @ Wl_h[:64] + bl_h))
//   Hn = (1-Z)*Ht          (R path multiplies H0=0 -> dead)
__global__ __launch_bounds__(1024) void k_prep(
        const float* __restrict__ deg, float* __restrict__ dinv,
        const int* __restrict__ counts, int* __restrict__ offsets,
        const float* __restrict__ Wg_z, const float* __restrict__ bg_z,
        const float* __restrict__ Wg_h, const float* __restrict__ bg_h,
        const float* __restrict__ Wl_z, const float* __restrict__ bl_z,
        const float* __restrict__ Wl_h, const float* __restrict__ bl_h,
        const float* __restrict__ att,
        uint2* __restrict__ wfrag, float* bz_eff, float* bh_eff, float* probs) {
    __shared__ float wzl[NF][NH + 1];
    __shared__ float whl[NF][NH + 1];
    int blk = blockIdx.x;
    int t = threadIdx.x;
    if (blk < 20) {                       // ---- dinv ----
        int i = blk * 1024 + t;
        if (i < NN) dinv[i] = rsqrtf(1.0f + deg[i]);   // +1 = self-loop weight
        return;
    }
    if (blk == 20) {                      // ---- exclusive scan counts -> offsets ----
        __shared__ int sums[1024];
        const int PER = (NN + 1023) / 1024; // 20
        int start = t * PER;
        int end   = start + PER; if (end > NN) end = NN;
        int s = 0;
        for (int i = start; i < end && start < NN; ++i) s += counts[i];
        if (start >= NN) s = 0;
        sums[t] = s;
        __syncthreads();
        for (int off = 1; off < 1024; off <<= 1) {
            int v = (t >= off) ? sums[t - off] : 0;
            __syncthreads();
            sums[t] += v;
            __syncthreads();
        }
        int run = (t == 0) ? 0 : sums[t - 1];
        for (int i = start; i < end && start < NN; ++i) { offsets[i] = run; run += counts[i]; }
        if (t == 1023) offsets[NN] = sums[1023]; // == NE
        return;
    }
    // ---- block 21: weight folding ----  t = f*64 + j
    {
        int f = t >> 6, j = t & 63;
        float sz = 0.f, sh = 0.f;
        for (int k = 0; k < NH; ++k) {
            sz += Wg_z[f * NH + k] * Wl_z[k * NH + j];
            sh += Wg_h[f * NH + k] * Wl_h[k * NH + j];
        }
        wzl[f][j] = sz;
        whl[f][j] = sh;
    }
    if (t < NH) {
        float bz = bl_z[t], bh = bl_h[t];
        for (int k = 0; k < NH; ++k) {
            bz += bg_z[k] * Wl_z[k * NH + t];
            bh += bg_h[k] * Wl_h[k * NH + t];
        }
        bz_eff[t] = bz;
        bh_eff[t] = bh;
    }
    if (t == 0) {
        float m = att[0];
        for (int p = 1; p < NP; ++p) m = fmaxf(m, att[p]);
        float s = 0.f, e_[NP];
        for (int p = 0; p < NP; ++p) { e_[p] = expf(att[p] - m); s += e_[p]; }
        for (int p = 0; p < 16; ++p) probs[p] = (p < NP) ? e_[p] / s : 0.f; // [12..15]=0: pad rows
    }
    __syncthreads();
    // ---- pack B-fragments for v_mfma_f32_16x16x16_f16 ----
    // lane ln supplies B[k = 4*(ln>>4)+i][n = ln&15] for chunk c (j = 16c+n).
    if (t < 512) {
        int ln = t & 63, c = (t >> 6) & 3, zh = t >> 8;
        int kb = 4 * (ln >> 4);
        int j  = 16 * c + (ln & 15);
        float v0, v1, v2, v3;
        if (zh == 0) { v0 = wzl[kb][j]; v1 = wzl[kb+1][j]; v2 = wzl[kb+2][j]; v3 = wzl[kb+3][j]; }
        else         { v0 = whl[kb][j]; v1 = whl[kb+1][j]; v2 = whl[kb+2][j]; v3 = whl[kb+3][j]; }
        union { _Float16 h[4]; uint2 u; } pk;
        pk.h[0] = (_Float16)v0; pk.h[1] = (_Float16)v1;
        pk.h[2] = (_Float16)v2; pk.h[3] = (_Float16)v3;
        wfrag[(zh * 4 + c) * 64 + ln] = pk.u;
    }
}

__global__ __launch_bounds__(256) void k_fill(const int* __restrict__ ei,
                                              const float* __restrict__ ew,
                                              const float* __restrict__ dinv,
                                              const int* __restrict__ offsets,
                                              int* cursor, int* src_list, float* norm_list) {
    int e = blockIdx.x * 256 + threadIdx.x;
    if (e < NE) {
        int s = ei[e];
        int d = ei[NE + e];
        float nm = dinv[s] * ew[e] * dinv[d];
        int pos = atomicAdd(&cursor[d], 1);
        int idx = offsets[d] + pos;
        src_list[idx]  = s;
        norm_list[idx] = nm;
    }
}

// ---------------- fused aggregate + MFMA-GRU + attention + output ----------------
// 1 block per node; wave w (of 4) handles batch w; waves independent (no barrier).
// Gather (round-5 measured-good): half-wave per edge, one dwordx3 of f16 per lane.
// GRU: A(16x16: 12 periods + 4 zero rows, K=16 features) @ B(16x64 z | 16x64 h)
// via 8x v_mfma_f32_16x16x16_f16 — replaces 192 readlane + 384 VALU fma.
__global__ __launch_bounds__(256) void k_main(
        const _Float16* __restrict__ xh,
        const int* __restrict__ offsets, const int* __restrict__ src_list,
        const float* __restrict__ norm_list, const float* __restrict__ dinv,
        const uint2* __restrict__ wfrag,
        const float* __restrict__ bz_eff, const float* __restrict__ bh_eff,
        const float* __restrict__ probs, const float* __restrict__ W_out,
        const float* __restrict__ b_out, float* __restrict__ out) {
    __shared__ float a_lds[NB][FP];
    int n = blockIdx.x;
    int b = threadIdx.x >> 6;
    int lane = threadIdx.x & 63;
    int half = lane >> 5;
    int L = lane & 31;

    const _Float16* xb = xh + (size_t)b * ((size_t)NN * FP);

    float a0=0.f,a1=0.f,a2=0.f,a3=0.f,a4=0.f,a5=0.f;

    auto acc = [&](float w, uint3 u) {
        union HU { unsigned u; _Float16 h[2]; };
        HU ux{u.x}, uy{u.y}, uz{u.z};
        a0 = fmaf(w, (float)ux.h[0], a0);
        a1 = fmaf(w, (float)ux.h[1], a1);
        a2 = fmaf(w, (float)uy.h[0], a2);
        a3 = fmaf(w, (float)uy.h[1], a3);
        a4 = fmaf(w, (float)uz.h[0], a4);
        a5 = fmaf(w, (float)uz.h[1], a5);
    };

    // self loop (half 0 carries the weight; half 1's load discarded via w=0)
    {
        float di = dinv[n];
        float w = half ? 0.f : di * di;
        uint3 u = *(const uint3*)(xb + (size_t)n * FP + L * 6);
        acc(w, u);
    }

    int beg = offsets[n], end = offsets[n + 1];
    int e = beg;
    for (; e + 4 <= end; e += 4) {                 // 4 edges, 2 dwordx3 in flight
        int i0 = e + half, i1 = e + 2 + half;
        int   sA = src_list[i0]; float wA = norm_list[i0];
        int   sB = src_list[i1]; float wB = norm_list[i1];
        uint3 uA = *(const uint3*)(xb + (size_t)sA * FP + L * 6);
        uint3 uB = *(const uint3*)(xb + (size_t)sB * FP + L * 6);
        acc(wA, uA);
        acc(wB, uB);
    }
    for (; e < end; e += 2) {                      // remainder (1 or 2 edges)
        int i0 = e + half;
        bool v = i0 < end;
        int ic = v ? i0 : e;
        int   s = src_list[ic];
        float w = v ? norm_list[ic] : 0.f;
        uint3 u = *(const uint3*)(xb + (size_t)s * FP + L * 6);
        acc(w, u);
    }

    // complete cross-half sums
    a0 += __shfl_xor(a0, 32, 64);
    a1 += __shfl_xor(a1, 32, 64);
    a2 += __shfl_xor(a2, 32, 64);
    a3 += __shfl_xor(a3, 32, 64);
    a4 += __shfl_xor(a4, 32, 64);
    a5 += __shfl_xor(a5, 32, 64);

    // stage a (element E = f*12+p) into LDS; lane L<32 owns E in [6L, 6L+6)
    if (lane < 32) {
        a_lds[b][6*L + 0] = a0; a_lds[b][6*L + 1] = a1; a_lds[b][6*L + 2] = a2;
        a_lds[b][6*L + 3] = a3; a_lds[b][6*L + 4] = a4; a_lds[b][6*L + 5] = a5;
    }
    // (same-wave ds_write -> ds_read: compiler inserts lgkmcnt; waves independent)

    // A-fragment: lane l holds A[p = l&15][f = 4*(l>>4)+i], i=0..3; rows p>=12 zero
    int g = lane >> 4, p = lane & 15;
    bool prow = p < NP;
    float af0, af1, af2, af3;
    {
        int base = 48 * g + p;
        int i0 = prow ? base      : 0;
        int i1 = prow ? base + 12 : 0;
        int i2 = prow ? base + 24 : 0;
        int i3 = prow ? base + 36 : 0;
        af0 = prow ? a_lds[b][i0] : 0.f;
        af1 = prow ? a_lds[b][i1] : 0.f;
        af2 = prow ? a_lds[b][i2] : 0.f;
        af3 = prow ? a_lds[b][i3] : 0.f;
    }
    h4_t A = { (_Float16)af0, (_Float16)af1, (_Float16)af2, (_Float16)af3 };

    // B-fragments + bias-initialized accumulators
    union FU { uint2 u; h4_t h; };
    f4_t accz[4], acch[4];
    h4_t Bz[4], Bh[4];
#pragma unroll
    for (int c = 0; c < 4; ++c) {
        FU fz; fz.u = wfrag[c * 64 + lane];       Bz[c] = fz.h;
        FU fh; fh.u = wfrag[(4 + c) * 64 + lane]; Bh[c] = fh.h;
        float bzv = bz_eff[16 * c + p];
        float bhv = bh_eff[16 * c + p];
        accz[c] = (f4_t){bzv, bzv, bzv, bzv};
        acch[c] = (f4_t){bhv, bhv, bhv, bhv};
    }
#pragma unroll
    for (int c = 0; c < 4; ++c) {
        accz[c] = __builtin_amdgcn_mfma_f32_16x16x16f16(A, Bz[c], accz[c], 0, 0, 0);
        acch[c] = __builtin_amdgcn_mfma_f32_16x16x16f16(A, Bh[c], acch[c], 0, 0, 0);
    }

    // D: lane l, chunk c, reg r -> period p' = 4*(l>>4)+r, hidden j = 16c+(l&15)
    float4 pr = *(const float4*)(probs + 4 * g);   // probs[p'] ; [12..15] == 0
    float hc0, hc1, hc2, hc3;
#pragma unroll
    for (int c = 0; c < 4; ++c) {
        float partial = 0.f;
#pragma unroll
        for (int r = 0; r < 4; ++r) {
            float zz = accz[c][r];
            float hh = acch[c][r];
            float sn = 1.f / (1.f + __expf(zz));              // 1 - sigmoid(z)
            float th = 1.f - 2.f / (__expf(2.f * hh) + 1.f);  // tanh(h)
            float prr = (r == 0) ? pr.x : (r == 1) ? pr.y : (r == 2) ? pr.z : pr.w;
            partial = fmaf(prr, sn * th, partial);
        }
        partial += __shfl_xor(partial, 16, 64);
        partial += __shfl_xor(partial, 32, 64);
        float v = fmaxf(partial, 0.f);
        if (c == 0) hc0 = v; else if (c == 1) hc1 = v; else if (c == 2) hc2 = v; else hc3 = v;
    }
    // select chunk c = g: lane l then holds relu(Hacc)[j = l]
    float r01 = (g & 1) ? hc1 : hc0;
    float r23 = (g & 1) ? hc3 : hc2;
    float rsel = (g & 2) ? r23 : r01;

    // output: out[k] = sum_j rsel(j) * W_out[j][k] + b_out[k]
    const float4* wrow = (const float4*)(W_out + lane * NP);
    float4 w0 = wrow[0], w1 = wrow[1], w2 = wrow[2];
    float o[NP];
    o[0] = rsel * w0.x; o[1]  = rsel * w0.y; o[2]  = rsel * w0.z; o[3]  = rsel * w0.w;
    o[4] = rsel * w1.x; o[5]  = rsel * w1.y; o[6]  = rsel * w1.z; o[7]  = rsel * w1.w;
    o[8] = rsel * w2.x; o[9]  = rsel * w2.y; o[10] = rsel * w2.z; o[11] = rsel * w2.w;
#pragma unroll
    for (int off = 32; off > 0; off >>= 1) {
#pragma unroll
        for (int k = 0; k < NP; ++k) o[k] += __shfl_xor(o[k], off, 64);
    }
    if (lane == 0) {
        const float4* bo = (const float4*)b_out;
        float4 b0 = bo[0], b1 = bo[1], b2 = bo[2];
        float4 r0 = { o[0] + b0.x, o[1] + b0.y, o[2]  + b0.z, o[3]  + b0.w };
        float4 r1 = { o[4] + b1.x, o[5] + b1.y, o[6]  + b1.z, o[7]  + b1.w };
        float4 r2 = { o[8] + b2.x, o[9] + b2.y, o[10] + b2.z, o[11] + b2.w };
        float4* op = (float4*)(out + ((size_t)b * NN + n) * NP);
        op[0] = r0; op[1] = r1; op[2] = r2;
    }
}

// ---------------- launch ----------------

extern "C" void kernel_launch(void* const* d_in, const int* in_sizes, int n_in,
                              void* d_out, int out_size, void* d_ws, size_t ws_size,
                              hipStream_t stream) {
    const float* x     = (const float*)d_in[0];
    const int*   ei    = (const int*)d_in[1];    // int32 per harness (shape [2][NE])
    const float* ew    = (const float*)d_in[2];
    const float* Wg_z  = (const float*)d_in[3];
    const float* bg_z  = (const float*)d_in[4];
    // d_in[5], d_in[6]: Wg_r/bg_r — dead (H0==0)
    const float* Wg_h  = (const float*)d_in[7];
    const float* bg_h  = (const float*)d_in[8];
    const float* Wl_z  = (const float*)d_in[9];
    const float* bl_z  = (const float*)d_in[10];
    // d_in[11], d_in[12]: Wl_r/bl_r — dead
    const float* Wl_h  = (const float*)d_in[13];
    const float* bl_h  = (const float*)d_in[14];
    const float* att   = (const float*)d_in[15];
    const float* W_out = (const float*)d_in[16];
    const float* b_out = (const float*)d_in[17];
    float*       out   = (float*)d_out;

    char* p = (char*)d_ws;
    auto alloc = [&](size_t bytes) -> void* {
        void* r = (void*)p;
        p += (bytes + 255) & ~(size_t)255;
        return r;
    };
    // deg/counts/cursor contiguous -> one memset zeroes all three
    const size_t PAD_NN = ((size_t)NN * 4 + 255) & ~(size_t)255;
    float*     deg       = (float*)alloc(NN * 4);
    int*       counts    = (int*)  alloc(NN * 4);
    int*       cursor    = (int*)  alloc(NN * 4);
    float*     dinv      = (float*)alloc(NN * 4);
    int*       offsets   = (int*)  alloc((NN + 1) * 4);
    int*       src_list  = (int*)  alloc(NE * 4);
    float*     norm_list = (float*)alloc(NE * 4);
    uint2*     wfrag     = (uint2*)alloc(512 * 8);     // [2][4][64] B-fragments
    float*     bz_eff    = (float*)alloc(NH * 4);
    float*     bh_eff    = (float*)alloc(NH * 4);
    float*     probs     = (float*)alloc(16 * 4);
    _Float16*  xh        = (_Float16*)alloc((size_t)NB * NN * FP * 2);  // 30.72 MB

    hipMemsetAsync(deg, 0, PAD_NN * 3, stream);

    k_pre1 <<<16250, 256, 0, stream>>>(x, xh, ei, ew, deg, counts);
    k_prep <<<22, 1024, 0, stream>>>(deg, dinv, counts, offsets,
                                     Wg_z, bg_z, Wg_h, bg_h, Wl_z, bl_z, Wl_h, bl_h, att,
                                     wfrag, bz_eff, bh_eff, probs);
    k_fill <<<(NE + 255) / 256, 256, 0, stream>>>(ei, ew, dinv, offsets, cursor, src_list, norm_list);
    k_main <<<NN, 256, 0, stream>>>(xh, offsets, src_list, norm_list, dinv,
                                    wfrag, bz_eff, bh_eff, probs, W_out, b_out, out);
}

// Round 7
// 232.091 us; speedup vs baseline: 4.0245x; 1.0442x over previous
//
#include <hip/hip_runtime.h>
#include <cstdint>
#include <cstddef>

#define NN 20000   // nodes
#define NE 320000  // edges
#define NB 4       // batch
#define NF 16      // f_in
#define NH 64      // hidden
#define NP 12      // periods
#define FP (NF*NP) // 192 features per node row

typedef _Float16 h2_t __attribute__((ext_vector_type(2)));
typedef _Float16 h4_t __attribute__((ext_vector_type(4)));
typedef float    f4_t __attribute__((ext_vector_type(4)));

union U32H2 { unsigned u; h2_t h; };
union U64H4 { uint2 u; h4_t h; };

// ---------------- convert x to fp16 + degree/count ----------------
// blocks [0, 15000): convert x (float4 -> 4 halves); blocks [15000, 16250): degcount.
__global__ __launch_bounds__(256) void k_pre1(const float* __restrict__ x,
                                              _Float16* __restrict__ xh,
                                              const int* __restrict__ ei,
                                              const float* __restrict__ ew,
                                              float* deg, int* counts) {
    int blk = blockIdx.x;
    if (blk < 15000) {
        int i = blk * 256 + threadIdx.x;
        float4 v = ((const float4*)x)[i];
        h4_t o = { (_Float16)v.x, (_Float16)v.y, (_Float16)v.z, (_Float16)v.w };
        ((h4_t*)xh)[i] = o;
    } else {
        int e = (blk - 15000) * 256 + threadIdx.x;
        int dst = ei[NE + e];
        atomicAdd(&deg[dst], ew[e]);
        atomicAdd(&counts[dst], 1);
    }
}

// Fused: blocks 0..19 -> dinv; block 20 -> scan; block 21 -> weight folding +
// f16 MFMA B-fragment packing (GRU z/h + output W_out) + biases + probs.
// H0 == 0 in the reference (carry is the accumulator), so:
//   Z  = sigmoid(a @ (Wg_z @ Wl_z[:64]) + (bg_z @ Wl_z[:64] + bl_z))
//   Ht = tanh  (a @ (Wg_h @ Wl_h[:64]) + (bg_h @ Wl_h[:64] + bl_h))
//   Hn = (1-Z)*Ht          (R path multiplies H0=0 -> dead)
__global__ __launch_bounds__(1024) void k_prep(
        const float* __restrict__ deg, float* __restrict__ dinv,
        const int* __restrict__ counts, int* __restrict__ offsets,
        const float* __restrict__ Wg_z, const float* __restrict__ bg_z,
        const float* __restrict__ Wg_h, const float* __restrict__ bg_h,
        const float* __restrict__ Wl_z, const float* __restrict__ bl_z,
        const float* __restrict__ Wl_h, const float* __restrict__ bl_h,
        const float* __restrict__ att, const float* __restrict__ W_out,
        uint2* __restrict__ wfrag, uint2* __restrict__ wofrag,
        float* bz_eff, float* bh_eff, float* probs) {
    __shared__ float wzl[NF][NH + 1];
    __shared__ float whl[NF][NH + 1];
    int blk = blockIdx.x;
    int t = threadIdx.x;
    if (blk < 20) {                       // ---- dinv ----
        int i = blk * 1024 + t;
        if (i < NN) dinv[i] = rsqrtf(1.0f + deg[i]);   // +1 = self-loop weight
        return;
    }
    if (blk == 20) {                      // ---- exclusive scan counts -> offsets ----
        __shared__ int sums[1024];
        const int PER = (NN + 1023) / 1024; // 20
        int start = t * PER;
        int end   = start + PER; if (end > NN) end = NN;
        int s = 0;
        for (int i = start; i < end && start < NN; ++i) s += counts[i];
        if (start >= NN) s = 0;
        sums[t] = s;
        __syncthreads();
        for (int off = 1; off < 1024; off <<= 1) {
            int v = (t >= off) ? sums[t - off] : 0;
            __syncthreads();
            sums[t] += v;
            __syncthreads();
        }
        int run = (t == 0) ? 0 : sums[t - 1];
        for (int i = start; i < end && start < NN; ++i) { offsets[i] = run; run += counts[i]; }
        if (t == 1023) offsets[NN] = sums[1023]; // == NE
        return;
    }
    // ---- block 21: weight folding ----  t = f*64 + j
    {
        int f = t >> 6, j = t & 63;
        float sz = 0.f, sh = 0.f;
        for (int k = 0; k < NH; ++k) {
            sz += Wg_z[f * NH + k] * Wl_z[k * NH + j];
            sh += Wg_h[f * NH + k] * Wl_h[k * NH + j];
        }
        wzl[f][j] = sz;
        whl[f][j] = sh;
    }
    if (t < NH) {
        float bz = bl_z[t], bh = bl_h[t];
        for (int k = 0; k < NH; ++k) {
            bz += bg_z[k] * Wl_z[k * NH + t];
            bh += bg_h[k] * Wl_h[k * NH + t];
        }
        bz_eff[t] = bz;
        bh_eff[t] = bh;
    }
    if (t == 0) {
        float m = att[0];
        for (int p = 1; p < NP; ++p) m = fmaxf(m, att[p]);
        float s = 0.f, e_[NP];
        for (int p = 0; p < NP; ++p) { e_[p] = expf(att[p] - m); s += e_[p]; }
        for (int p = 0; p < 16; ++p) probs[p] = (p < NP) ? e_[p] / s : 0.f; // [12..15]=0: pad rows
    }
    __syncthreads();
    // ---- GRU B-fragments (z,h): lane ln supplies B[k=4*(ln>>4)+i][n=ln&15], chunk c ----
    if (t < 512) {
        int ln = t & 63, c = (t >> 6) & 3, zh = t >> 8;
        int kb = 4 * (ln >> 4);
        int j  = 16 * c + (ln & 15);
        float v0, v1, v2, v3;
        if (zh == 0) { v0 = wzl[kb][j]; v1 = wzl[kb+1][j]; v2 = wzl[kb+2][j]; v3 = wzl[kb+3][j]; }
        else         { v0 = whl[kb][j]; v1 = whl[kb+1][j]; v2 = whl[kb+2][j]; v3 = whl[kb+3][j]; }
        union { _Float16 h[4]; uint2 u; } pk;
        pk.h[0] = (_Float16)v0; pk.h[1] = (_Float16)v1;
        pk.h[2] = (_Float16)v2; pk.h[3] = (_Float16)v3;
        wfrag[(zh * 4 + c) * 64 + ln] = pk.u;
    }
    // ---- output B-fragments: k-step s, B[k=16s+4*(ln>>4)+i][n=ln&15] = W_out[k][n] ----
    if (t < 256) {
        int ln = t & 63, s = t >> 6;
        int kj = 16 * s + 4 * (ln >> 4);
        int nn_ = ln & 15;
        union { _Float16 h[4]; uint2 u; } pk;
        for (int i = 0; i < 4; ++i)
            pk.h[i] = (_Float16)((nn_ < NP) ? W_out[(kj + i) * NP + nn_] : 0.f);
        wofrag[s * 64 + ln] = pk.u;
    }
}

// edge records: {byte offset of src row (s*384), norm as packed f16 pair}
__global__ __launch_bounds__(256) void k_fill(const int* __restrict__ ei,
                                              const float* __restrict__ ew,
                                              const float* __restrict__ dinv,
                                              const int* __restrict__ offsets,
                                              int* cursor, uint2* __restrict__ erec) {
    int e = blockIdx.x * 256 + threadIdx.x;
    if (e < NE) {
        int s = ei[e];
        int d = ei[NE + e];
        float nm = dinv[s] * ew[e] * dinv[d];
        int pos = atomicAdd(&cursor[d], 1);
        int idx = offsets[d] + pos;
        _Float16 hn = (_Float16)nm;
        U32H2 w; w.h = (h2_t){hn, hn};
        erec[idx] = make_uint2((unsigned)(s * (FP * 2)), w.u);
    }
}

// ---------------- fused aggregate + MFMA-GRU + attention + MFMA-output ----------------
// 1 block per node; wave w (of 4) handles batch w. Gather: half-wave per edge,
// one dwordx3 of f16 per lane, v_pk_fma_f16 accumulation (f16, 3 ops/edge).
// GRU: 8x mfma_16x16x16_f16 (A = 12 periods + 4 clamped rows, K=16 features).
// Output: each wave parks relu(H) as f16 in LDS; after the block's only
// barrier, wave 0 computes out = r @ W_out + b_out for ALL 4 batches with
// 4 MFMAs (M rows = batches) — replaces 4x(72 shfl + 84 VALU) butterflies.
__global__ __launch_bounds__(256) void k_main(
        const _Float16* __restrict__ xh,
        const int* __restrict__ offsets, const uint2* __restrict__ erec,
        const float* __restrict__ dinv,
        const uint2* __restrict__ wfrag, const uint2* __restrict__ wofrag,
        const float* __restrict__ bz_eff, const float* __restrict__ bh_eff,
        const float* __restrict__ probs, const float* __restrict__ b_out,
        float* __restrict__ out) {
    __shared__ _Float16 a_lds[NB][FP];     // 1.5 KB aggregated features
    __shared__ _Float16 r_lds[16][NH];     // 2 KB relu(H); rows 4..15 unwritten (D rows independent)
    int n = blockIdx.x;
    int b = threadIdx.x >> 6;
    int lane = threadIdx.x & 63;
    int half = lane >> 5;
    int L = lane & 31;
    int g = lane >> 4, p = lane & 15;

    const char* xb = (const char*)(xh + (size_t)b * ((size_t)NN * FP));
    int lb = L * 12;

    h2_t A0 = {(_Float16)0.f, (_Float16)0.f};
    h2_t A1 = A0, A2 = A0;

    auto accp = [&](unsigned wb, uint3 u) {
        U32H2 w;  w.u  = wb;
        U32H2 x0; x0.u = u.x;
        U32H2 x1; x1.u = u.y;
        U32H2 x2; x2.u = u.z;
        A0 += w.h * x0.h;      // v_pk_fma_f16
        A1 += w.h * x1.h;
        A2 += w.h * x2.h;
    };

    // self loop (half 0 carries the weight; half 1's load discarded via w=0)
    {
        float di = dinv[n];
        float swf = half ? 0.f : di * di;
        _Float16 sh = (_Float16)swf;
        U32H2 w; w.h = (h2_t){sh, sh};
        uint3 u = *(const uint3*)(xb + n * (FP * 2) + lb);
        accp(w.u, u);
    }

    int beg = offsets[n], end = offsets[n + 1];
    int e = beg;
    for (; e + 8 <= end; e += 8) {          // 8 edges, 4 dwordx3/lane in flight
        uint2 r0 = erec[e + half];
        uint2 r1 = erec[e + 2 + half];
        uint2 r2 = erec[e + 4 + half];
        uint2 r3 = erec[e + 6 + half];
        uint3 u0 = *(const uint3*)(xb + r0.x + lb);
        uint3 u1 = *(const uint3*)(xb + r1.x + lb);
        uint3 u2 = *(const uint3*)(xb + r2.x + lb);
        uint3 u3 = *(const uint3*)(xb + r3.x + lb);
        accp(r0.y, u0); accp(r1.y, u1); accp(r2.y, u2); accp(r3.y, u3);
    }
    for (; e < end; e += 2) {               // remainder, masked via w=0
        int i0 = e + half;
        bool v = i0 < end;
        uint2 r0 = erec[v ? i0 : e];
        uint3 u0 = *(const uint3*)(xb + r0.x + lb);
        accp(v ? r0.y : 0u, u0);
    }

    // cross-half reduce (3 shfl + 3 pk_add)
    {
        U32H2 t0, t1, t2, s0, s1, s2;
        t0.h = A0; t1.h = A1; t2.h = A2;
        s0.u = (unsigned)__shfl_xor((int)t0.u, 32, 64);
        s1.u = (unsigned)__shfl_xor((int)t1.u, 32, 64);
        s2.u = (unsigned)__shfl_xor((int)t2.u, 32, 64);
        A0 += s0.h; A1 += s1.h; A2 += s2.h;
    }

    // stage a into LDS (packed); lane L<32 owns elements [6L, 6L+6)
    if (lane < 32) {
        unsigned* aw = (unsigned*)&a_lds[b][0];
        U32H2 t0, t1, t2; t0.h = A0; t1.h = A1; t2.h = A2;
        aw[3 * L + 0] = t0.u;
        aw[3 * L + 1] = t1.u;
        aw[3 * L + 2] = t2.u;
    }
    // same-wave ds_write -> ds_read: DS ops are in-order within a wave

    // A-fragment: A[p][f=4g+i] = a[(4g+i)*12 + p]; pad rows p>=12 clamp to row 0
    // (duplicate finite data; probs[12..15]=0 kills their contribution)
    int pe = (p < NP) ? p : 0;
    const _Float16* ab = &a_lds[b][48 * g + pe];
    h4_t A = { ab[0], ab[12], ab[24], ab[36] };

    U64H4 fz[4], fh[4];
    f4_t accz[4], acch[4];
#pragma unroll
    for (int c = 0; c < 4; ++c) {
        fz[c].u = wfrag[c * 64 + lane];
        fh[c].u = wfrag[(4 + c) * 64 + lane];
        float bzv = bz_eff[16 * c + p];
        float bhv = bh_eff[16 * c + p];
        accz[c] = (f4_t){bzv, bzv, bzv, bzv};
        acch[c] = (f4_t){bhv, bhv, bhv, bhv};
    }
#pragma unroll
    for (int c = 0; c < 4; ++c) {
        accz[c] = __builtin_amdgcn_mfma_f32_16x16x16f16(A, fz[c].h, accz[c], 0, 0, 0);
        acch[c] = __builtin_amdgcn_mfma_f32_16x16x16f16(A, fh[c].h, acch[c], 0, 0, 0);
    }

    // D: lane l, chunk c, reg r -> period p' = 4g+r, hidden j = 16c+p
    float4 pr = *(const float4*)(probs + 4 * g);   // probs[p']; [12..15] == 0
#pragma unroll
    for (int c = 0; c < 4; ++c) {
        float partial = 0.f;
#pragma unroll
        for (int r = 0; r < 4; ++r) {
            float zz = accz[c][r];
            float hh = acch[c][r];
            float sn = 1.f / (1.f + __expf(zz));              // 1 - sigmoid(z)
            float th = 1.f - 2.f / (__expf(2.f * hh) + 1.f);  // tanh(h)
            float prr = (r == 0) ? pr.x : (r == 1) ? pr.y : (r == 2) ? pr.z : pr.w;
            partial = fmaf(prr, sn * th, partial);
        }
        partial += __shfl_xor(partial, 16, 64);   // pool over period groups
        partial += __shfl_xor(partial, 32, 64);
        r_lds[b][16 * c + p] = (_Float16)fmaxf(partial, 0.f);  // relu(H)[j=16c+p]
    }
    __syncthreads();

    // wave 0: out[batch][n][k] = r @ W_out + b_out for all 4 batches via 4 MFMAs.
    // A rows m = batch (0..3 real, 4..15 garbage -> D rows independent, unread).
    if (threadIdx.x < 64) {
        float bo = b_out[p < NP ? p : 0];
        f4_t co = (f4_t){bo, bo, bo, bo};
#pragma unroll
        for (int s = 0; s < 4; ++s) {
            h4_t Ao = *(const h4_t*)&r_lds[p][16 * s + 4 * g];  // ds_read_b64
            U64H4 Bo; Bo.u = wofrag[s * 64 + lane];
            co = __builtin_amdgcn_mfma_f32_16x16x16f16(Ao, Bo.h, co, 0, 0, 0);
        }
        // D: col k = p, row = 4g + r = batch; take g==0 lanes
        if (g == 0 && p < NP) {
            size_t baseo = (size_t)n * NP + p;
#pragma unroll
            for (int r = 0; r < 4; ++r)
                out[(size_t)r * ((size_t)NN * NP) + baseo] = co[r];
        }
    }
}

// ---------------- launch ----------------

extern "C" void kernel_launch(void* const* d_in, const int* in_sizes, int n_in,
                              void* d_out, int out_size, void* d_ws, size_t ws_size,
                              hipStream_t stream) {
    const float* x     = (const float*)d_in[0];
    const int*   ei    = (const int*)d_in[1];    // int32 per harness (shape [2][NE])
    const float* ew    = (const float*)d_in[2];
    const float* Wg_z  = (const float*)d_in[3];
    const float* bg_z  = (const float*)d_in[4];
    // d_in[5], d_in[6]: Wg_r/bg_r — dead (H0==0)
    const float* Wg_h  = (const float*)d_in[7];
    const float* bg_h  = (const float*)d_in[8];
    const float* Wl_z  = (const float*)d_in[9];
    const float* bl_z  = (const float*)d_in[10];
    // d_in[11], d_in[12]: Wl_r/bl_r — dead
    const float* Wl_h  = (const float*)d_in[13];
    const float* bl_h  = (const float*)d_in[14];
    const float* att   = (const float*)d_in[15];
    const float* W_out = (const float*)d_in[16];
    const float* b_out = (const float*)d_in[17];
    float*       out   = (float*)d_out;

    char* p = (char*)d_ws;
    auto alloc = [&](size_t bytes) -> void* {
        void* r = (void*)p;
        p += (bytes + 255) & ~(size_t)255;
        return r;
    };
    // deg/counts/cursor contiguous -> one memset zeroes all three
    const size_t PAD_NN = ((size_t)NN * 4 + 255) & ~(size_t)255;
    float*     deg     = (float*)alloc(NN * 4);
    int*       counts  = (int*)  alloc(NN * 4);
    int*       cursor  = (int*)  alloc(NN * 4);
    float*     dinv    = (float*)alloc(NN * 4);
    int*       offsets = (int*)  alloc((NN + 1) * 4);
    uint2*     erec    = (uint2*)alloc((size_t)NE * 8);   // {src byte off, f16x2 norm}
    uint2*     wfrag   = (uint2*)alloc(512 * 8);          // GRU z/h B-fragments
    uint2*     wofrag  = (uint2*)alloc(256 * 8);          // output B-fragments
    float*     bz_eff  = (float*)alloc(NH * 4);
    float*     bh_eff  = (float*)alloc(NH * 4);
    float*     probs   = (float*)alloc(16 * 4);
    _Float16*  xh      = (_Float16*)alloc((size_t)NB * NN * FP * 2);  // 30.72 MB

    hipMemsetAsync(deg, 0, PAD_NN * 3, stream);

    k_pre1 <<<16250, 256, 0, stream>>>(x, xh, ei, ew, deg, counts);
    k_prep <<<22, 1024, 0, stream>>>(deg, dinv, counts, offsets,
                                     Wg_z, bg_z, Wg_h, bg_h, Wl_z, bl_z, Wl_h, bl_h,
                                     att, W_out, wfrag, wofrag, bz_eff, bh_eff, probs);
    k_fill <<<(NE + 255) / 256, 256, 0, stream>>>(ei, ew, dinv, offsets, cursor, erec);
    k_main <<<NN, 256, 0, stream>>>(xh, offsets, erec, dinv,
                                    wfrag, wofrag, bz_eff, bh_eff, probs, b_out, out);
}

// Round 8
// 217.824 us; speedup vs baseline: 4.2881x; 1.0655x over previous
//
#include <hip/hip_runtime.h>
#include <cstdint>
#include <cstddef>

#define NN 20000   // nodes
#define NE 320000  // edges
#define NB 4       // batch
#define NF 16      // f_in
#define NH 64      // hidden
#define NP 12      // periods
#define FP (NF*NP) // 192 features per node row
#define GRID_MAIN 2000   // persistent blocks: 10 nodes each

typedef _Float16 h2_t __attribute__((ext_vector_type(2)));
typedef _Float16 h4_t __attribute__((ext_vector_type(4)));
typedef float    f4_t __attribute__((ext_vector_type(4)));

union U32H2 { unsigned u; h2_t h; };
union U64H4 { uint2 u; h4_t h; };

// ---------------- convert x to fp16 + degree/count ----------------
// blocks [0, 15000): convert x (float4 -> 4 halves); blocks [15000, 16250): degcount.
__global__ __launch_bounds__(256) void k_pre1(const float* __restrict__ x,
                                              _Float16* __restrict__ xh,
                                              const int* __restrict__ ei,
                                              const float* __restrict__ ew,
                                              float* deg, int* counts) {
    int blk = blockIdx.x;
    if (blk < 15000) {
        int i = blk * 256 + threadIdx.x;
        float4 v = ((const float4*)x)[i];
        h4_t o = { (_Float16)v.x, (_Float16)v.y, (_Float16)v.z, (_Float16)v.w };
        ((h4_t*)xh)[i] = o;
    } else {
        int e = (blk - 15000) * 256 + threadIdx.x;
        int dst = ei[NE + e];
        atomicAdd(&deg[dst], ew[e]);
        atomicAdd(&counts[dst], 1);
    }
}

// Fused: blocks 0..19 -> dinv; block 20 -> scan (offsets include +1 self-edge
// slot per node); block 21 -> weight folding + f16 MFMA B-fragments + biases.
// H0 == 0 in the reference (carry is the accumulator), so:
//   Z  = sigmoid(a @ (Wg_z @ Wl_z[:64]) + (bg_z @ Wl_z[:64] + bl_z))
//   Ht = tanh  (a @ (Wg_h @ Wl_h[:64]) + (bg_h @ Wl_h[:64] + bl_h))
//   Hn = (1-Z)*Ht          (R path multiplies H0=0 -> dead)
__global__ __launch_bounds__(1024) void k_prep(
        const float* __restrict__ deg, float* __restrict__ dinv,
        const int* __restrict__ counts, int* __restrict__ offsets,
        const float* __restrict__ Wg_z, const float* __restrict__ bg_z,
        const float* __restrict__ Wg_h, const float* __restrict__ bg_h,
        const float* __restrict__ Wl_z, const float* __restrict__ bl_z,
        const float* __restrict__ Wl_h, const float* __restrict__ bl_h,
        const float* __restrict__ att, const float* __restrict__ W_out,
        uint2* __restrict__ wfrag, uint2* __restrict__ wofrag,
        float* bz_eff, float* bh_eff, float* probs) {
    __shared__ float wzl[NF][NH + 1];
    __shared__ float whl[NF][NH + 1];
    int blk = blockIdx.x;
    int t = threadIdx.x;
    if (blk < 20) {                       // ---- dinv ----
        int i = blk * 1024 + t;
        if (i < NN) dinv[i] = rsqrtf(1.0f + deg[i]);   // +1 = self-loop weight
        return;
    }
    if (blk == 20) {    // ---- scan: offsets[i] = prefix(counts) + i (self-edge slots) ----
        __shared__ int sums[1024];
        const int PER = (NN + 1023) / 1024; // 20
        int start = t * PER;
        int end   = start + PER; if (end > NN) end = NN;
        int s = 0;
        for (int i = start; i < end && start < NN; ++i) s += counts[i];
        if (start >= NN) s = 0;
        sums[t] = s;
        __syncthreads();
        for (int off = 1; off < 1024; off <<= 1) {
            int v = (t >= off) ? sums[t - off] : 0;
            __syncthreads();
            sums[t] += v;
            __syncthreads();
        }
        int run = (t == 0) ? 0 : sums[t - 1];
        for (int i = start; i < end && start < NN; ++i) { offsets[i] = run + i; run += counts[i]; }
        if (t == 1023) offsets[NN] = sums[1023] + NN; // == NE + NN
        return;
    }
    // ---- block 21: weight folding ----  t = f*64 + j
    {
        int f = t >> 6, j = t & 63;
        float sz = 0.f, sh = 0.f;
        for (int k = 0; k < NH; ++k) {
            sz += Wg_z[f * NH + k] * Wl_z[k * NH + j];
            sh += Wg_h[f * NH + k] * Wl_h[k * NH + j];
        }
        wzl[f][j] = sz;
        whl[f][j] = sh;
    }
    if (t < NH) {
        float bz = bl_z[t], bh = bl_h[t];
        for (int k = 0; k < NH; ++k) {
            bz += bg_z[k] * Wl_z[k * NH + t];
            bh += bg_h[k] * Wl_h[k * NH + t];
        }
        bz_eff[t] = bz;
        bh_eff[t] = bh;
    }
    if (t == 0) {
        float m = att[0];
        for (int p = 1; p < NP; ++p) m = fmaxf(m, att[p]);
        float s = 0.f, e_[NP];
        for (int p = 0; p < NP; ++p) { e_[p] = expf(att[p] - m); s += e_[p]; }
        for (int p = 0; p < 16; ++p) probs[p] = (p < NP) ? e_[p] / s : 0.f; // [12..15]=0: pad rows
    }
    __syncthreads();
    // ---- GRU B-fragments (z,h): lane ln supplies B[k=4*(ln>>4)+i][n=ln&15], chunk c ----
    if (t < 512) {
        int ln = t & 63, c = (t >> 6) & 3, zh = t >> 8;
        int kb = 4 * (ln >> 4);
        int j  = 16 * c + (ln & 15);
        float v0, v1, v2, v3;
        if (zh == 0) { v0 = wzl[kb][j]; v1 = wzl[kb+1][j]; v2 = wzl[kb+2][j]; v3 = wzl[kb+3][j]; }
        else         { v0 = whl[kb][j]; v1 = whl[kb+1][j]; v2 = whl[kb+2][j]; v3 = whl[kb+3][j]; }
        union { _Float16 h[4]; uint2 u; } pk;
        pk.h[0] = (_Float16)v0; pk.h[1] = (_Float16)v1;
        pk.h[2] = (_Float16)v2; pk.h[3] = (_Float16)v3;
        wfrag[(zh * 4 + c) * 64 + ln] = pk.u;
    }
    // ---- output B-fragments: k-step s, B[k=16s+4*(ln>>4)+i][n=ln&15] = W_out[k][n] ----
    if (t < 256) {
        int ln = t & 63, s = t >> 6;
        int kj = 16 * s + 4 * (ln >> 4);
        int nn_ = ln & 15;
        union { _Float16 h[4]; uint2 u; } pk;
        for (int i = 0; i < 4; ++i)
            pk.h[i] = (_Float16)((nn_ < NP) ? W_out[(kj + i) * NP + nn_] : 0.f);
        wofrag[s * 64 + ln] = pk.u;
    }
}

// edge records {src row byte offset, f16x2 norm}; threads >= NE write the
// per-node self-edge into the reserved last slot offsets[n+1]-1.
__global__ __launch_bounds__(256) void k_fill(const int* __restrict__ ei,
                                              const float* __restrict__ ew,
                                              const float* __restrict__ dinv,
                                              const int* __restrict__ offsets,
                                              int* cursor, uint2* __restrict__ erec) {
    int e = blockIdx.x * 256 + threadIdx.x;
    if (e < NE) {
        int s = ei[e];
        int d = ei[NE + e];
        float nm = dinv[s] * ew[e] * dinv[d];
        int pos = atomicAdd(&cursor[d], 1);
        int idx = offsets[d] + pos;
        _Float16 hn = (_Float16)nm;
        U32H2 w; w.h = (h2_t){hn, hn};
        erec[idx] = make_uint2((unsigned)(s * (FP * 2)), w.u);
    } else if (e < NE + NN) {
        int node = e - NE;
        float di = dinv[node];
        _Float16 hn = (_Float16)(di * di);
        U32H2 w; w.h = (h2_t){hn, hn};
        erec[offsets[node + 1] - 1] = make_uint2((unsigned)(node * (FP * 2)), w.u);
    }
}

// ---------------- persistent fused aggregate + MFMA-GRU + attention + output ----
// GRID_MAIN blocks, grid-stride over nodes (10 nodes/block). Weights/biases/
// probs preloaded into LDS ONCE per block. Wave w = batch w. Edge records
// read wave-uniformly (s_load), per-half select via cndmask. r_lds double-
// buffered (one barrier per node), row stride 72 halves, write g==0 only.
__global__ __launch_bounds__(256) void k_main(
        const _Float16* __restrict__ xh,
        const int* __restrict__ offsets, const uint2* __restrict__ erec,
        const uint2* __restrict__ wfrag, const uint2* __restrict__ wofrag,
        const float* __restrict__ bz_eff, const float* __restrict__ bh_eff,
        const float* __restrict__ probs, const float* __restrict__ b_out,
        float* __restrict__ out) {
    __shared__ _Float16 a_lds[NB][FP];          // per-wave aggregated features
    __shared__ _Float16 r_lds[2][NB][NH + 8];   // double-buffered relu(H), padded
    __shared__ uint2    wz_lds[512];            // GRU z/h B-fragments
    __shared__ uint2    wo_lds[256];            // output B-fragments
    __shared__ float    bzh_lds[128];           // bz_eff | bh_eff
    __shared__ float    pr_lds[16];
    __shared__ float    bo_lds[12];

    int t = threadIdx.x;
    wz_lds[t]       = wfrag[t];
    wz_lds[t + 256] = wfrag[t + 256];
    wo_lds[t]       = wofrag[t];
    if (t < 128) bzh_lds[t] = (t < 64) ? bz_eff[t] : bh_eff[t - 64];
    if (t < 16)  pr_lds[t] = probs[t];
    if (t < 12)  bo_lds[t] = b_out[t];
    __syncthreads();

    int b = t >> 6;
    int lane = t & 63;
    int half = lane >> 5;
    int L = lane & 31;
    int g = lane >> 4, p = lane & 15;

    const char* xb = (const char*)(xh + (size_t)b * ((size_t)NN * FP));
    int lb = L * 12;

    int it = 0;
    for (int n = blockIdx.x; n < NN; n += GRID_MAIN, ++it) {
        int beg = offsets[n], end = offsets[n + 1];   // uniform -> s_load

        h2_t A0 = {(_Float16)0.f, (_Float16)0.f};
        h2_t A1 = A0, A2 = A0;
        auto accp = [&](unsigned wb, uint3 u) {
            U32H2 w;  w.u  = wb;
            U32H2 x0; x0.u = u.x;
            U32H2 x1; x1.u = u.y;
            U32H2 x2; x2.u = u.z;
            A0 += w.h * x0.h;      // v_pk_fma_f16
            A1 += w.h * x1.h;
            A2 += w.h * x2.h;
        };

        int e = beg;
        for (; e + 8 <= end; e += 8) {     // 8 edges: 8 s_load pairs, 4 rows in flight
            uint2 q0 = erec[e+0], q1 = erec[e+1], q2 = erec[e+2], q3 = erec[e+3];
            uint2 q4 = erec[e+4], q5 = erec[e+5], q6 = erec[e+6], q7 = erec[e+7];
            unsigned o0 = half ? q1.x : q0.x, w0 = half ? q1.y : q0.y;
            unsigned o1 = half ? q3.x : q2.x, w1 = half ? q3.y : q2.y;
            unsigned o2 = half ? q5.x : q4.x, w2 = half ? q5.y : q4.y;
            unsigned o3 = half ? q7.x : q6.x, w3 = half ? q7.y : q6.y;
            uint3 u0 = *(const uint3*)(xb + o0 + lb);
            uint3 u1 = *(const uint3*)(xb + o1 + lb);
            uint3 u2 = *(const uint3*)(xb + o2 + lb);
            uint3 u3 = *(const uint3*)(xb + o3 + lb);
            accp(w0, u0); accp(w1, u1); accp(w2, u2); accp(w3, u3);
        }
        for (; e < end; e += 2) {          // remainder (1 or 2 edges), mask via w=0
            uint2 q0 = erec[e];
            int e1 = (e + 1 < end) ? e + 1 : e;
            uint2 q1 = erec[e1];
            unsigned w1m = (e + 1 < end) ? q1.y : 0u;
            unsigned off = half ? q1.x : q0.x;
            unsigned wn  = half ? w1m  : q0.y;
            uint3 u = *(const uint3*)(xb + off + lb);
            accp(wn, u);
        }

        // cross-half reduce (3 shfl + 3 pk_add)
        {
            U32H2 t0, t1, t2, s0, s1, s2;
            t0.h = A0; t1.h = A1; t2.h = A2;
            s0.u = (unsigned)__shfl_xor((int)t0.u, 32, 64);
            s1.u = (unsigned)__shfl_xor((int)t1.u, 32, 64);
            s2.u = (unsigned)__shfl_xor((int)t2.u, 32, 64);
            A0 += s0.h; A1 += s1.h; A2 += s2.h;
        }

        // stage a into LDS (packed); lane L<32 owns elements [6L, 6L+6)
        if (lane < 32) {
            unsigned* aw = (unsigned*)&a_lds[b][0];
            U32H2 t0, t1, t2; t0.h = A0; t1.h = A1; t2.h = A2;
            aw[3 * L + 0] = t0.u;
            aw[3 * L + 1] = t1.u;
            aw[3 * L + 2] = t2.u;
        }
        // same-wave ds_write -> ds_read: in program order within a wave

        // A-fragment: A[p][f=4g+i] = a[(4g+i)*12 + p]; pad rows p>=12 clamp to row 0
        int pe = (p < NP) ? p : 0;
        const _Float16* ab = &a_lds[b][48 * g + pe];
        h4_t A = { ab[0], ab[12], ab[24], ab[36] };

        f4_t accz[4], acch[4];
#pragma unroll
        for (int c = 0; c < 4; ++c) {
            float bzv = bzh_lds[16 * c + p];
            float bhv = bzh_lds[64 + 16 * c + p];
            accz[c] = (f4_t){bzv, bzv, bzv, bzv};
            acch[c] = (f4_t){bhv, bhv, bhv, bhv};
        }
#pragma unroll
        for (int c = 0; c < 4; ++c) {
            U64H4 fz; fz.u = wz_lds[c * 64 + lane];
            U64H4 fh; fh.u = wz_lds[(4 + c) * 64 + lane];
            accz[c] = __builtin_amdgcn_mfma_f32_16x16x16f16(A, fz.h, accz[c], 0, 0, 0);
            acch[c] = __builtin_amdgcn_mfma_f32_16x16x16f16(A, fh.h, acch[c], 0, 0, 0);
        }

        // D: lane l, chunk c, reg r -> period p' = 4g+r, hidden j = 16c+p
#pragma unroll
        for (int c = 0; c < 4; ++c) {
            float partial = 0.f;
#pragma unroll
            for (int r = 0; r < 4; ++r) {
                float zz = accz[c][r];
                float hh = acch[c][r];
                float sn = 1.f / (1.f + __expf(zz));              // 1 - sigmoid(z)
                float th = 1.f - 2.f / (__expf(2.f * hh) + 1.f);  // tanh(h)
                partial = fmaf(pr_lds[4 * g + r], sn * th, partial);
            }
            partial += __shfl_xor(partial, 16, 64);   // pool over period groups
            partial += __shfl_xor(partial, 32, 64);
            if (g == 0) r_lds[it & 1][b][16 * c + p] = (_Float16)fmaxf(partial, 0.f);
        }
        __syncthreads();

        // wave 0: out[batch][n][k] = r @ W_out + b_out for all 4 batches, 4 MFMAs.
        if (t < 64) {
            float bo = bo_lds[p < NP ? p : 0];
            f4_t co = (f4_t){bo, bo, bo, bo};
            int pb = p & 3;     // batch row (rows 4..15 duplicate -> D rows unread)
#pragma unroll
            for (int s = 0; s < 4; ++s) {
                h4_t Ao = *(const h4_t*)&r_lds[it & 1][pb][16 * s + 4 * g];
                U64H4 Bo; Bo.u = wo_lds[s * 64 + lane];
                co = __builtin_amdgcn_mfma_f32_16x16x16f16(Ao, Bo.h, co, 0, 0, 0);
            }
            // D: col k = p, row = 4g + r = batch; take g==0 lanes
            if (g == 0 && p < NP) {
                size_t baseo = (size_t)n * NP + p;
#pragma unroll
                for (int r = 0; r < 4; ++r)
                    out[(size_t)r * ((size_t)NN * NP) + baseo] = co[r];
            }
        }
    }
}

// ---------------- launch ----------------

extern "C" void kernel_launch(void* const* d_in, const int* in_sizes, int n_in,
                              void* d_out, int out_size, void* d_ws, size_t ws_size,
                              hipStream_t stream) {
    const float* x     = (const float*)d_in[0];
    const int*   ei    = (const int*)d_in[1];    // int32 per harness (shape [2][NE])
    const float* ew    = (const float*)d_in[2];
    const float* Wg_z  = (const float*)d_in[3];
    const float* bg_z  = (const float*)d_in[4];
    // d_in[5], d_in[6]: Wg_r/bg_r — dead (H0==0)
    const float* Wg_h  = (const float*)d_in[7];
    const float* bg_h  = (const float*)d_in[8];
    const float* Wl_z  = (const float*)d_in[9];
    const float* bl_z  = (const float*)d_in[10];
    // d_in[11], d_in[12]: Wl_r/bl_r — dead
    const float* Wl_h  = (const float*)d_in[13];
    const float* bl_h  = (const float*)d_in[14];
    const float* att   = (const float*)d_in[15];
    const float* W_out = (const float*)d_in[16];
    const float* b_out = (const float*)d_in[17];
    float*       out   = (float*)d_out;

    char* p = (char*)d_ws;
    auto alloc = [&](size_t bytes) -> void* {
        void* r = (void*)p;
        p += (bytes + 255) & ~(size_t)255;
        return r;
    };
    // deg/counts/cursor contiguous -> one memset zeroes all three
    const size_t PAD_NN = ((size_t)NN * 4 + 255) & ~(size_t)255;
    float*     deg     = (float*)alloc(NN * 4);
    int*       counts  = (int*)  alloc(NN * 4);
    int*       cursor  = (int*)  alloc(NN * 4);
    float*     dinv    = (float*)alloc(NN * 4);
    int*       offsets = (int*)  alloc((NN + 1) * 4);
    uint2*     erec    = (uint2*)alloc((size_t)(NE + NN) * 8); // edges + self-edges
    uint2*     wfrag   = (uint2*)alloc(512 * 8);               // GRU z/h B-fragments
    uint2*     wofrag  = (uint2*)alloc(256 * 8);               // output B-fragments
    float*     bz_eff  = (float*)alloc(NH * 4);
    float*     bh_eff  = (float*)alloc(NH * 4);
    float*     probs   = (float*)alloc(16 * 4);
    _Float16*  xh      = (_Float16*)alloc((size_t)NB * NN * FP * 2);  // 30.72 MB

    hipMemsetAsync(deg, 0, PAD_NN * 3, stream);

    k_pre1 <<<16250, 256, 0, stream>>>(x, xh, ei, ew, deg, counts);
    k_prep <<<22, 1024, 0, stream>>>(deg, dinv, counts, offsets,
                                     Wg_z, bg_z, Wg_h, bg_h, Wl_z, bl_z, Wl_h, bl_h,
                                     att, W_out, wfrag, wofrag, bz_eff, bh_eff, probs);
    k_fill <<<(NE + NN + 255) / 256, 256, 0, stream>>>(ei, ew, dinv, offsets, cursor, erec);
    k_main <<<GRID_MAIN, 256, 0, stream>>>(xh, offsets, erec,
                                           wfrag, wofrag, bz_eff, bh_eff, probs, b_out, out);
}